// Round 8
// baseline (2266.785 us; speedup 1.0000x reference)
//
#include <hip/hip_runtime.h>
#include <math.h>

// ---------------------------------------------------------------------------
// DyRes/CondConv AlexNet forward. R8: R7 (pre-split bf16 hi/lo weight planes,
// packed-u32 B staging, 3-product double-bf16 MFMA, split-K atomics) plus a
// register double-buffer pipeline in the K-loop: tile k+1's global loads are
// issued into registers before computing tile k from LDS, so gather latency
// overlaps MFMA instead of serializing at the barrier.
// Tile 128Mx128N, BK=32, 4 waves (64x64 each).
// ---------------------------------------------------------------------------

typedef unsigned short u16;
typedef unsigned int u32;
typedef short bf16x8 __attribute__((ext_vector_type(8)));
typedef float f32x4 __attribute__((ext_vector_type(4)));

__device__ __forceinline__ u16 bf16_rne(float f) {
    u32 u = __float_as_uint(f);
    return (u16)((u + 0x7fffu + ((u >> 16) & 1u)) >> 16);
}
__device__ __forceinline__ u32 packsplit(float v) {
    u16 h = bf16_rne(v);
    float hf = __uint_as_float((u32)h << 16);
    u16 l = bf16_rne(v - hf);
    return ((u32)h << 16) | l;
}
__device__ __forceinline__ float unpackf(u32 p) {
    return __uint_as_float(p & 0xffff0000u) + __uint_as_float(p << 16);
}

// fp32 weights -> K-padded bf16 hi/lo planes (zero-padded beyond Kper)
__global__ __launch_bounds__(256)
void wsplit_kernel(const float* __restrict__ W, u16* __restrict__ whi,
                   u16* __restrict__ wlo, int total, int Kper, int Kpad)
{
    int idx = blockIdx.x * 256 + threadIdx.x;
    if (idx >= total) return;
    int r = idx / Kpad, k = idx - r * Kpad;
    float v = (k < Kper) ? W[(size_t)r * Kper + k] : 0.f;
    u16 h = bf16_rne(v);
    whi[idx] = h;
    wlo[idx] = bf16_rne(v - __uint_as_float((u32)h << 16));
}

__global__ __launch_bounds__(64)
void stats_kernel(const void* __restrict__ actv, float* __restrict__ s,
                  int Bsz, int C, int HW, int cbhw, int use_std, int packed)
{
    int idx = blockIdx.x;           // b*C + c
    int b = idx / C, c = idx - b * C;
    size_t base = (cbhw ? ((size_t)c * Bsz + b) : ((size_t)b * C + c)) * HW;
    int lane = threadIdx.x;
    float sum = 0.f, sq = 0.f;
    if (packed) {
        const u32* p = (const u32*)actv + base;
        for (int i = lane; i < HW; i += 64) { float v = unpackf(p[i]); sum += v; sq += v * v; }
    } else {
        const float* p = (const float*)actv + base;
        for (int i = lane; i < HW; i += 64) { float v = p[i]; sum += v; sq += v * v; }
    }
#pragma unroll
    for (int off = 32; off > 0; off >>= 1) {
        sum += __shfl_down(sum, off);
        sq  += __shfl_down(sq, off);
    }
    if (lane == 0) {
        float inv = 1.f / (float)HW;
        float mean = sum * inv;
        float var = sq * inv - mean * mean;
        float outv = mean;
        if (use_std) outv += sqrtf(fmaxf(var, 0.f));
        s[idx] = outv;
    }
}

__global__ __launch_bounds__(64)
void routing_kernel(const float* __restrict__ s, const float* __restrict__ rw,
                    const float* __restrict__ rb, float* __restrict__ r,
                    int C, int softmax_mode)
{
    int b = blockIdx.x;
    int lane = threadIdx.x;
    float d0 = 0.f, d1 = 0.f, d2 = 0.f;
    for (int c = lane; c < C; c += 64) {
        float sv = s[b * C + c];
        d0 += sv * rw[c];
        d1 += sv * rw[C + c];
        d2 += sv * rw[2 * C + c];
    }
#pragma unroll
    for (int off = 32; off > 0; off >>= 1) {
        d0 += __shfl_down(d0, off);
        d1 += __shfl_down(d1, off);
        d2 += __shfl_down(d2, off);
    }
    if (lane == 0) {
        d0 += rb[0]; d1 += rb[1]; d2 += rb[2];
        if (softmax_mode) {
            float mx = fmaxf(d0, fmaxf(d1, d2));
            float e0 = expf(d0 - mx), e1 = expf(d1 - mx), e2 = expf(d2 - mx);
            float inv = 1.f / (e0 + e1 + e2);
            r[b * 3 + 0] = e0 * inv;
            r[b * 3 + 1] = e1 * inv;
            r[b * 3 + 2] = e2 * inv;
        } else {
            r[b * 3 + 0] = 1.f / (1.f + expf(-d0));
            r[b * 3 + 1] = 1.f / (1.f + expf(-d1));
            r[b * 3 + 2] = 1.f / (1.f + expf(-d2));
        }
    }
}

// padded im2col k-decode: kk in [0, 3*Kpad); pad entries get OOB sentinel kh=15
__global__ __launch_bounds__(256)
void ktab_kernel(int2* __restrict__ tab, int Kpad, int Kper, int chanStride, int W)
{
    int kk = blockIdx.x * 256 + threadIdx.x;
    if (kk >= 3 * Kpad) return;
    int e = kk / Kpad;
    int kq = kk - e * Kpad;
    if (kq >= Kper) { tab[kk] = make_int2(0, 15 << 4); return; }
    int ci = kq / 9;
    int r9 = kq - ci * 9;
    int kh = r9 / 3;
    int kw = r9 - kh * 3;
    tab[kk] = make_int2(ci * chanStride + kh * W + kw, (kh << 4) | (kw << 2));
}

// ---------------------------------------------------------------------------
// MFMA GEMM, 128Mx128N tile, BK=32, register double-buffered K-loop.
// A from pre-split bf16 hi/lo planes (row eA*M+m, stride Kpad, zero-padded).
// B packed u32: BMODE 0 plain [n][Kpad]; 1 gather [Ci,B,H,W]; 2 gather [B,Ci,H,W].
// Products al*bh + ah*bl + ah*bh, fp32 acc; epilogue r-scale (convs),
// bias (bz==0), fp32 atomicAdd into pre-zeroed Cout.
// Kchunk must be a multiple of 32 (guaranteed by padding).
// ---------------------------------------------------------------------------
template<int BMODE, int BIAS, int TROUT>
__global__ __launch_bounds__(256)
void mgemm_kernel(const u16* __restrict__ Whi, const u16* __restrict__ Wlo,
                  const u32* __restrict__ Bpk, const int2* __restrict__ ktab,
                  const float* __restrict__ rptr, const float* __restrict__ bias,
                  float* __restrict__ Cout,
                  int M, int N, int Kpad, int Kchunk, int zpe,
                  int Ci, int Bsz, int H, int W, int lgS, int lgOW, int stride)
{
    __shared__ __align__(16) u16 Ah[128 * 40], Al[128 * 40];
    __shared__ __align__(16) u32 Bp[128 * 36];
    const int tid = threadIdx.x;
    const int n0 = blockIdx.x << 7, m0 = blockIdx.y << 7;
    const int bz = blockIdx.z;
    const int eA = bz / zpe;
    const int kq0 = (bz - eA * zpe) * Kchunk;
    const int nIter = Kchunk >> 5;

    const int rowA = tid >> 1, kh16 = (tid & 1) << 4;   // A: 2 thr/row, 16 bf16
    const int nB = tid & 127, kOff = (tid >> 7) << 4;   // B: 16 u32 per thread

    int ohs = 0, ows = 0; long nBase = 0;
    if (BMODE != 0) {
        int nn = n0 + nB;
        int bB = nn >> lgS;
        int sidx = nn & ((1 << lgS) - 1);
        ohs = (sidx >> lgOW) * stride - 1;
        ows = (sidx & ((1 << lgOW) - 1)) * stride - 1;
        long bOff = (BMODE == 2) ? (long)bB * Ci * H * W : (long)bB * H * W;
        nBase = bOff + (long)ohs * W + ows;
    }

    const int lane = tid & 63, wv = tid >> 6;
    const int lm = lane & 15, qd = lane >> 4;
    const int wm = (wv & 1) << 6, wn = (wv >> 1) << 6;

    f32x4 acc[4][4];
#pragma unroll
    for (int i = 0; i < 4; ++i)
#pragma unroll
        for (int j = 0; j < 4; ++j)
            acc[i][j] = (f32x4){0.f, 0.f, 0.f, 0.f};

    const size_t aRowBase = (size_t)eA * M;
    const int mgA = m0 + rowA;
    const bool mokA = mgA < M;
    const u16* hpBase = Whi + (aRowBase + (mokA ? mgA : 0)) * (size_t)Kpad + kh16;
    const u16* lpBase = Wlo + (aRowBase + (mokA ? mgA : 0)) * (size_t)Kpad + kh16;

    // prefetch registers
    uint4 pAh0, pAh1, pAl0, pAl1;
    u32 pB[16];

    auto loadTile = [&](int kq) {
        // A planes: pure b128 loads
        if (mokA) {
            pAh0 = *(const uint4*)(hpBase + kq);
            pAh1 = *(const uint4*)(hpBase + kq + 8);
            pAl0 = *(const uint4*)(lpBase + kq);
            pAl1 = *(const uint4*)(lpBase + kq + 8);
        } else {
            pAh0 = pAh1 = pAl0 = pAl1 = make_uint4(0, 0, 0, 0);
        }
        // B
        if (BMODE == 0) {
            const u32* bp = Bpk + (size_t)(n0 + nB) * Kpad + kq + kOff;
            *(uint4*)(&pB[0])  = *(const uint4*)bp;
            *(uint4*)(&pB[4])  = *(const uint4*)(bp + 4);
            *(uint4*)(&pB[8])  = *(const uint4*)(bp + 8);
            *(uint4*)(&pB[12]) = *(const uint4*)(bp + 12);
        } else {
#pragma unroll
            for (int j = 0; j < 16; ++j) {
                int kkG = eA * Kpad + kq + kOff + j;
                int2 t = ktab[kkG];
                int ih = ohs + (t.y >> 4), iw = ows + ((t.y >> 2) & 3);
                u32 p = 0;
                if ((unsigned)ih < (unsigned)H && (unsigned)iw < (unsigned)W)
                    p = Bpk[nBase + t.x];
                pB[j] = p;
            }
        }
    };

    auto storeTile = [&]() {
        *(uint4*)(&Ah[rowA * 40 + kh16])     = pAh0;
        *(uint4*)(&Ah[rowA * 40 + kh16 + 8]) = pAh1;
        *(uint4*)(&Al[rowA * 40 + kh16])     = pAl0;
        *(uint4*)(&Al[rowA * 40 + kh16 + 8]) = pAl1;
        *(uint4*)(&Bp[nB * 36 + kOff])      = *(const uint4*)(&pB[0]);
        *(uint4*)(&Bp[nB * 36 + kOff + 4])  = *(const uint4*)(&pB[4]);
        *(uint4*)(&Bp[nB * 36 + kOff + 8])  = *(const uint4*)(&pB[8]);
        *(uint4*)(&Bp[nB * 36 + kOff + 12]) = *(const uint4*)(&pB[12]);
    };

    auto compute = [&]() {
        bf16x8 ah[4], al[4];
#pragma unroll
        for (int mi = 0; mi < 4; ++mi) {
            int row = wm + mi * 16 + lm;
            ah[mi] = *(const bf16x8*)(&Ah[row * 40 + qd * 8]);
            al[mi] = *(const bf16x8*)(&Al[row * 40 + qd * 8]);
        }
#pragma unroll
        for (int ni = 0; ni < 4; ++ni) {
            int row = wn + ni * 16 + lm;
            const u32* bp = &Bp[row * 36 + qd * 8];
            uint4 p0 = *(const uint4*)bp;
            uint4 p1 = *(const uint4*)(bp + 4);
            union { u32 w[4]; bf16x8 v; } bh, bl;
            bh.w[0] = (p0.x >> 16) | (p0.y & 0xffff0000u);
            bl.w[0] = (p0.x & 0xffffu) | (p0.y << 16);
            bh.w[1] = (p0.z >> 16) | (p0.w & 0xffff0000u);
            bl.w[1] = (p0.z & 0xffffu) | (p0.w << 16);
            bh.w[2] = (p1.x >> 16) | (p1.y & 0xffff0000u);
            bl.w[2] = (p1.x & 0xffffu) | (p1.y << 16);
            bh.w[3] = (p1.z >> 16) | (p1.w & 0xffff0000u);
            bl.w[3] = (p1.z & 0xffffu) | (p1.w << 16);
#pragma unroll
            for (int mi = 0; mi < 4; ++mi) {
                f32x4 c = acc[mi][ni];
                c = __builtin_amdgcn_mfma_f32_16x16x32_bf16(al[mi], bh.v, c, 0, 0, 0);
                c = __builtin_amdgcn_mfma_f32_16x16x32_bf16(ah[mi], bl.v, c, 0, 0, 0);
                c = __builtin_amdgcn_mfma_f32_16x16x32_bf16(ah[mi], bh.v, c, 0, 0, 0);
                acc[mi][ni] = c;
            }
        }
    };

    // ---- pipelined K-loop: load k+1 into regs, compute k from LDS ----
    loadTile(kq0);
    storeTile();
    __syncthreads();
    for (int it = 1; it < nIter; ++it) {
        loadTile(kq0 + (it << 5));   // global issue overlaps compute below
        compute();
        __syncthreads();
        storeTile();                 // vmcnt wait lands here
        __syncthreads();
    }
    compute();

    // ---- epilogue: r-scale (convs), bias (z0), fp32 atomicAdd ----
#pragma unroll
    for (int ni = 0; ni < 4; ++ni) {
        int n = n0 + wn + ni * 16 + lm;
        if (n >= N) continue;
        float rs = 1.f;
        if (BMODE != 0) rs = rptr[(n >> lgS) * 3 + eA];
#pragma unroll
        for (int mi = 0; mi < 4; ++mi)
#pragma unroll
            for (int r = 0; r < 4; ++r) {
                int m = m0 + wm + mi * 16 + qd * 4 + r;
                if (m >= M) continue;
                float v = acc[mi][ni][r];
                if (BMODE != 0) v *= rs;
                if (BIAS && bz == 0) v += bias[m];
                if (TROUT) atomicAdd(&Cout[(size_t)n * M + m], v);
                else       atomicAdd(&Cout[(size_t)m * N + n], v);
            }
    }
}

// elementwise fp32 -> packed bf16x2 (optional relu)
__global__ __launch_bounds__(256)
void pack_kernel(const float* __restrict__ in, u32* __restrict__ outp,
                 int count, int relu)
{
    int i = blockIdx.x * 256 + threadIdx.x;
    if (i >= count) return;
    float v = in[i];
    if (relu) v = fmaxf(v, 0.f);
    outp[i] = packsplit(v);
}

// 2x2/2 maxpool + relu, fp32 in -> packed out
template<int RELU>
__global__ __launch_bounds__(256)
void pool_pack_kernel(const float* __restrict__ in, u32* __restrict__ outp,
                      int CB, int H, int W)
{
    int OH = H >> 1, OW = W >> 1;
    int total = CB * OH * OW;
    int i = blockIdx.x * 256 + threadIdx.x;
    if (i >= total) return;
    int ow = i % OW;
    int t = i / OW;
    int oh = t % OH;
    int cb = t / OH;
    const float* p = in + ((size_t)cb * H + (oh << 1)) * W + (ow << 1);
    float v = fmaxf(fmaxf(p[0], p[1]), fmaxf(p[W], p[W + 1]));
    if (RELU) v = fmaxf(v, 0.f);
    outp[i] = packsplit(v);
}

// conv5 fp32 [256,512,4,4] --relu+pool--> packed hT [b][1024]
__global__ __launch_bounds__(256)
void pool_flatten_pack_kernel(const float* __restrict__ in, u32* __restrict__ outp)
{
    int i = blockIdx.x * 256 + threadIdx.x;
    if (i >= 512 * 1024) return;
    int b = i >> 10;
    int f = i & 1023;
    int c = f >> 2, s = f & 3;
    int oh = s >> 1, ow = s & 1;
    const float* p = in + (((size_t)c * 512 + b) * 4 + (oh << 1)) * 4 + (ow << 1);
    float v = fmaxf(fmaxf(p[0], p[1]), fmaxf(p[4], p[5]));
    outp[i] = packsplit(fmaxf(v, 0.f));
}

// FC act: fp32 [Mt][Nt] --relu--> packed transposed [Nt][Mt]
__global__ __launch_bounds__(256)
void tp_pack_kernel(const float* __restrict__ in, u32* __restrict__ outp,
                    int Mt, int Nt)
{
    __shared__ float t[32][33];
    int tx = threadIdx.x & 31, ty = threadIdx.x >> 5;
    int mB = blockIdx.x << 5, nB = blockIdx.y << 5;
#pragma unroll
    for (int i = 0; i < 4; ++i) {
        int mm = ty + i * 8;
        t[mm][tx] = in[(size_t)(mB + mm) * Nt + nB + tx];
    }
    __syncthreads();
#pragma unroll
    for (int i = 0; i < 4; ++i) {
        int nn = ty + i * 8;
        float v = fmaxf(t[tx][nn], 0.f);
        outp[(size_t)(nB + nn) * Mt + mB + tx] = packsplit(v);
    }
}

extern "C" void kernel_launch(void* const* d_in, const int* in_sizes, int n_in,
                              void* d_out, int out_size, void* d_ws, size_t ws_size,
                              hipStream_t stream)
{
    const float* x    = (const float*)d_in[0];
    const float* dw1  = (const float*)d_in[1];
    const float* rw1  = (const float*)d_in[2];
    const float* rb1  = (const float*)d_in[3];
    const float* dw2  = (const float*)d_in[4];
    const float* rw2  = (const float*)d_in[5];
    const float* rb2  = (const float*)d_in[6];
    const float* dw3  = (const float*)d_in[7];
    const float* rw3  = (const float*)d_in[8];
    const float* rb3  = (const float*)d_in[9];
    const float* cw4  = (const float*)d_in[10];
    const float* cr4w = (const float*)d_in[11];
    const float* cr4b = (const float*)d_in[12];
    const float* cw5  = (const float*)d_in[13];
    const float* cr5w = (const float*)d_in[14];
    const float* cr5b = (const float*)d_in[15];
    const float* fw1  = (const float*)d_in[16];
    const float* fb1  = (const float*)d_in[17];
    const float* fw2  = (const float*)d_in[18];
    const float* fb2  = (const float*)d_in[19];
    const float* fw3  = (const float*)d_in[20];
    const float* fb3  = (const float*)d_in[21];
    float* out = (float*)d_out;

    // workspace (float units); total ~25.4M floats ~= 102 MB
    float* ws    = (float*)d_ws;
    float* r1    = ws;
    float* r2    = r1 + 1536;
    float* r3    = r2 + 1536;
    float* r4    = r3 + 1536;
    float* r5    = r4 + 1536;
    int2*  tabs  = (int2*)(ws + 8192);
    int2*  t1    = tabs;
    int2*  t2    = tabs + 1024;
    int2*  t3    = tabs + 4096;
    int2*  t4    = tabs + 12288;
    int2*  t5    = tabs + 24576;
    float* sdesc = ws + 8192 + 65536;
    const size_t REGION = 18874368;
    float* region = sdesc + 196608;
    float* slab   = region;
    u16*   regEnd = (u16*)(region + REGION);
    u32*   P1     = (u32*)(region + REGION);
    u32*   P2     = P1 + 3145728;

    u16 *w1h = regEnd - 2*(size_t)6144,     *w1l = regEnd - (size_t)6144;
    u16 *w2h = regEnd - 2*(size_t)331776,   *w2l = regEnd - (size_t)331776;
    u16 *w3h = regEnd - 2*(size_t)1990656,  *w3l = regEnd - (size_t)1990656;
    u16 *w4h = regEnd - 2*(size_t)2654208,  *w4l = regEnd - (size_t)2654208;
    u16 *w5h = regEnd - 2*(size_t)1769472,  *w5l = regEnd - (size_t)1769472;
    u16 *f1h = regEnd - 2*(size_t)4194304,  *f1l = regEnd - (size_t)4194304;
    u16 *f2h = regEnd - 2*(size_t)16777216, *f2l = regEnd - (size_t)16777216;
    u16 *f3h = regEnd - 2*(size_t)409600,   *f3l = regEnd - (size_t)409600;

    u32* xpk   = P1;
    u32* a1pk  = P2;
    u32* a2pk  = P1;
    u32* c3pk  = P2;
    u32* c4pk  = P1;
    u32* hTpk  = P2;
    u32* f1pkT = P1;
    u32* f2pkT = P2;

    const int B = 512;

    // ---- decode tables + input pack ----
    ktab_kernel<<<1, 256, 0, stream>>>(t1, 32, 27, 1024, 32);
    ktab_kernel<<<7, 256, 0, stream>>>(t2, 576, 576, 32768, 8);
    ktab_kernel<<<21, 256, 0, stream>>>(t3, 1728, 1728, 8192, 4);
    ktab_kernel<<<41, 256, 0, stream>>>(t4, 3456, 3456, 8192, 4);
    ktab_kernel<<<27, 256, 0, stream>>>(t5, 2304, 2304, 8192, 4);
    pack_kernel<<<6144, 256, 0, stream>>>(x, xpk, 1572864, 0);

    // ---- Layer 1: DyRes conv 3->64, s2 p1 -> slab [64, 131072] ----
    wsplit_kernel<<<24, 256, 0, stream>>>(dw1, w1h, w1l, 6144, 27, 32);
    stats_kernel<<<B * 3, 64, 0, stream>>>(x, sdesc, B, 3, 1024, 0, 1, 0);
    routing_kernel<<<B, 64, 0, stream>>>(sdesc, rw1, rb1, r1, 3, 1);
    hipMemsetAsync(slab, 0, (size_t)64 * 131072 * 4, stream);
    mgemm_kernel<2, 0, 0><<<dim3(1024, 1, 3), 256, 0, stream>>>(
        w1h, w1l, xpk, t1, r1, nullptr, slab, 64, 131072, 32, 32, 1, 3, B, 32, 32, 8, 4, 2);
    pool_pack_kernel<1><<<8192, 256, 0, stream>>>(slab, a1pk, 64 * 512, 16, 16);

    // ---- Layer 2: DyRes conv 64->192 -> slab [192, 32768] ----
    wsplit_kernel<<<1296, 256, 0, stream>>>(dw2, w2h, w2l, 331776, 576, 576);
    stats_kernel<<<B * 64, 64, 0, stream>>>(a1pk, sdesc, B, 64, 64, 1, 1, 1);
    routing_kernel<<<B, 64, 0, stream>>>(sdesc, rw2, rb2, r2, 64, 1);
    hipMemsetAsync(slab, 0, (size_t)192 * 32768 * 4, stream);
    mgemm_kernel<1, 0, 0><<<dim3(256, 2, 3), 256, 0, stream>>>(
        w2h, w2l, a1pk, t2, r2, nullptr, slab, 192, 32768, 576, 576, 1, 64, B, 8, 8, 6, 3, 1);
    pool_pack_kernel<1><<<6144, 256, 0, stream>>>(slab, a2pk, 192 * 512, 8, 8);

    // ---- Layer 3: DyRes conv 192->384 -> slab [384, 8192] ----
    wsplit_kernel<<<7776, 256, 0, stream>>>(dw3, w3h, w3l, 1990656, 1728, 1728);
    stats_kernel<<<B * 192, 64, 0, stream>>>(a2pk, sdesc, B, 192, 16, 1, 1, 1);
    routing_kernel<<<B, 64, 0, stream>>>(sdesc, rw3, rb3, r3, 192, 1);
    hipMemsetAsync(slab, 0, (size_t)384 * 8192 * 4, stream);
    mgemm_kernel<1, 0, 0><<<dim3(64, 3, 6), 256, 0, stream>>>(
        w3h, w3l, a2pk, t3, r3, nullptr, slab, 384, 8192, 1728, 864, 2, 192, B, 4, 4, 4, 2, 1);
    pack_kernel<<<12288, 256, 0, stream>>>(slab, c3pk, 3145728, 1);

    // ---- Layer 4: CondConv 384->256 -> slab [256, 8192] ----
    wsplit_kernel<<<10368, 256, 0, stream>>>(cw4, w4h, w4l, 2654208, 3456, 3456);
    stats_kernel<<<B * 384, 64, 0, stream>>>(c3pk, sdesc, B, 384, 16, 1, 0, 1);
    routing_kernel<<<B, 64, 0, stream>>>(sdesc, cr4w, cr4b, r4, 384, 0);
    hipMemsetAsync(slab, 0, (size_t)256 * 8192 * 4, stream);
    mgemm_kernel<1, 0, 0><<<dim3(64, 2, 6), 256, 0, stream>>>(
        w4h, w4l, c3pk, t4, r4, nullptr, slab, 256, 8192, 3456, 1728, 2, 384, B, 4, 4, 4, 2, 1);
    pack_kernel<<<8192, 256, 0, stream>>>(slab, c4pk, 2097152, 1);

    // ---- Layer 5: CondConv 256->256 -> slab [256, 8192] ----
    wsplit_kernel<<<6912, 256, 0, stream>>>(cw5, w5h, w5l, 1769472, 2304, 2304);
    stats_kernel<<<B * 256, 64, 0, stream>>>(c4pk, sdesc, B, 256, 16, 1, 0, 1);
    routing_kernel<<<B, 64, 0, stream>>>(sdesc, cr5w, cr5b, r5, 256, 0);
    hipMemsetAsync(slab, 0, (size_t)256 * 8192 * 4, stream);
    mgemm_kernel<1, 0, 0><<<dim3(64, 2, 6), 256, 0, stream>>>(
        w5h, w5l, c4pk, t5, r5, nullptr, slab, 256, 8192, 2304, 1152, 2, 256, B, 4, 4, 4, 2, 1);

    // ---- relu + pool + flatten -> packed hT [512][1024] ----
    pool_flatten_pack_kernel<<<2048, 256, 0, stream>>>(slab, hTpk);

    // ---- FC1: 1024 -> 4096 ----
    wsplit_kernel<<<16384, 256, 0, stream>>>(fw1, f1h, f1l, 4194304, 1024, 1024);
    hipMemsetAsync(slab, 0, (size_t)4096 * 512 * 4, stream);
    mgemm_kernel<0, 1, 0><<<dim3(4, 32, 8), 256, 0, stream>>>(
        f1h, f1l, hTpk, nullptr, nullptr, fb1, slab, 4096, 512, 1024, 128, 8, 0, 0, 0, 0, 0, 0, 0);
    tp_pack_kernel<<<dim3(128, 16), 256, 0, stream>>>(slab, f1pkT, 4096, 512);

    // ---- FC2: 4096 -> 4096 ----
    wsplit_kernel<<<65536, 256, 0, stream>>>(fw2, f2h, f2l, 16777216, 4096, 4096);
    hipMemsetAsync(slab, 0, (size_t)4096 * 512 * 4, stream);
    mgemm_kernel<0, 1, 0><<<dim3(4, 32, 8), 256, 0, stream>>>(
        f2h, f2l, f1pkT, nullptr, nullptr, fb2, slab, 4096, 512, 4096, 512, 8, 0, 0, 0, 0, 0, 0, 0);
    tp_pack_kernel<<<dim3(128, 16), 256, 0, stream>>>(slab, f2pkT, 4096, 512);

    // ---- FC3: 4096 -> 100 -> d_out [512, 100] ----
    wsplit_kernel<<<1600, 256, 0, stream>>>(fw3, f3h, f3l, 409600, 4096, 4096);
    hipMemsetAsync(out, 0, (size_t)512 * 100 * 4, stream);
    mgemm_kernel<0, 1, 1><<<dim3(4, 1, 32), 256, 0, stream>>>(
        f3h, f3l, f2pkT, nullptr, nullptr, fb3, out, 100, 512, 4096, 128, 32, 0, 0, 0, 0, 0, 0, 0);
}